// Round 1
// baseline (371.843 us; speedup 1.0000x reference)
//
#include <hip/hip_runtime.h>

typedef unsigned short u16;
typedef __bf16 bf16_t;
typedef bf16_t bf16x8 __attribute__((ext_vector_type(8)));
typedef float f32x4 __attribute__((ext_vector_type(4)));
typedef u16 u16x8 __attribute__((ext_vector_type(8)));

__device__ __forceinline__ u16 f2bf(float f) {
  unsigned u = __float_as_uint(f);
  u += 0x7fffu + ((u >> 16) & 1u);
  return (u16)(u >> 16);
}

__device__ __forceinline__ f32x4 mfma16(bf16x8 a, bf16x8 b, f32x4 c) {
  return __builtin_amdgcn_mfma_f32_16x16x32_bf16(a, b, c, 0, 0, 0);
}

// ---------------- fp32 -> bf16 cast ----------------
__global__ __launch_bounds__(256) void castf2b(const float* __restrict__ in,
                                               u16* __restrict__ out, int n) {
  int i = blockIdx.x * 256 + threadIdx.x;
  if (i < n) out[i] = f2bf(in[i]);
}

// ---------------- GEMM: C[M][N] = A[M][K] * B[N][K]^T ----------------
// bf16 inputs, f32 output. Requires M%128==0, N%128==0, K%32==0.
__global__ __launch_bounds__(256) void gemm_bt(const u16* __restrict__ A,
                                               const u16* __restrict__ B,
                                               float* __restrict__ C,
                                               int M, int N, int K) {
  __shared__ u16 As[128][40];
  __shared__ u16 Bs[128][40];
  const int tid = threadIdx.x;
  const int lane = tid & 63;
  const int lg = lane >> 4, li = lane & 15;
  const int wave = tid >> 6;
  const int wr = (wave >> 1) * 64, wc = (wave & 1) * 64;
  const int m0 = blockIdx.y * 128, n0 = blockIdx.x * 128;
  const int lr = tid >> 1, lc = (tid & 1) * 16;

  const f32x4 fz = {0.f, 0.f, 0.f, 0.f};
  f32x4 acc[4][4];
#pragma unroll
  for (int i = 0; i < 4; i++)
#pragma unroll
    for (int j = 0; j < 4; j++) acc[i][j] = fz;

  for (int k0 = 0; k0 < K; k0 += 32) {
    const u16* ag = &A[(size_t)(m0 + lr) * K + k0 + lc];
    const u16* bg = &B[(size_t)(n0 + lr) * K + k0 + lc];
    *(u16x8*)&As[lr][lc] = *(const u16x8*)ag;
    *(u16x8*)&As[lr][lc + 8] = *(const u16x8*)(ag + 8);
    *(u16x8*)&Bs[lr][lc] = *(const u16x8*)bg;
    *(u16x8*)&Bs[lr][lc + 8] = *(const u16x8*)(bg + 8);
    __syncthreads();
    bf16x8 af[4], bfr[4];
#pragma unroll
    for (int i = 0; i < 4; i++)
      af[i] = *(const bf16x8*)&As[wr + i * 16 + li][lg * 8];
#pragma unroll
    for (int j = 0; j < 4; j++)
      bfr[j] = *(const bf16x8*)&Bs[wc + j * 16 + li][lg * 8];
#pragma unroll
    for (int i = 0; i < 4; i++)
#pragma unroll
      for (int j = 0; j < 4; j++) acc[i][j] = mfma16(af[i], bfr[j], acc[i][j]);
    __syncthreads();
  }
#pragma unroll
  for (int i = 0; i < 4; i++)
#pragma unroll
    for (int j = 0; j < 4; j++)
#pragma unroll
      for (int r = 0; r < 4; r++)
        C[(size_t)(m0 + wr + i * 16 + lg * 4 + r) * N + n0 + wc + j * 16 + li] =
            acc[i][j][r];
}

// ---------------- fused RMSNorm + RoPE + gain, scatter to head-major bf16 ----
// in: [B*S][ld] f32 rows; out: [B][nh][S][64] bf16
__global__ __launch_bounds__(64) void rmsrope(const float* __restrict__ in, int ld,
                                              int nh, const float* __restrict__ gain,
                                              u16* __restrict__ out, int S) {
  const int row = blockIdx.x;  // b*S + s
  const int h = blockIdx.y;
  const int t = threadIdx.x;   // 0..63
  const float v = in[(size_t)row * ld + h * 64 + t];
  float ss = v * v;
#pragma unroll
  for (int m = 1; m < 64; m <<= 1) ss += __shfl_xor(ss, m);
  const float vn = v * rsqrtf(ss * (1.0f / 64.0f) + 1.1920929e-07f);
  const float partner = __shfl_xor(vn, 32);
  const int i = t & 31;
  const float inv = powf(10000.0f, -(float)(2 * i) / 64.0f);
  const int b = row / S;
  const int s = row - b * S;
  const float fr = (float)s * inv;
  float sn, cs;
  sincosf(fr, &sn, &cs);
  // lane<32 holds t1: t1*cos + t2*sin ; lane>=32 holds t2: -t1*sin + t2*cos
  float o = (t < 32) ? (vn * cs + partner * sn) : (vn * cs - partner * sn);
  if (gain) o *= gain[h];
  out[((size_t)(b * nh + h) * S + s) * 64 + t] = f2bf(o);
}

// ---------------- V cast+transpose: kvf[B*S][512] cols 256..511 -> [B][4][64][S]
__global__ __launch_bounds__(256) void vcast(const float* __restrict__ kvf,
                                             u16* __restrict__ vt, int S) {
  int idx = blockIdx.x * 256 + threadIdx.x;  // over B*S*256
  int row = idx >> 8;  // b*S + s
  int c = idx & 255;   // kv*64 + d
  int b = row / S, s = row - b * S;
  int kv = c >> 6, d = c & 63;
  vt[((size_t)(b * 4 + kv) * 64 + d) * S + s] = f2bf(kvf[(size_t)row * 512 + 256 + c]);
}

// ---------------- flash attention: 1 wave per (b,h,16-row q tile) ------------
// qh: [B][16][S][64] bf16, kh: [B][4][S][64] bf16, vt: [B][4][64][S] bf16,
// y:  [B*S][1024] bf16
__global__ __launch_bounds__(64) void attn(const u16* __restrict__ qh,
                                           const u16* __restrict__ kh,
                                           const u16* __restrict__ vt,
                                           u16* __restrict__ y, int S) {
  const int nqt = S >> 4;
  const int qt = blockIdx.x % nqt;
  const int bh = blockIdx.x / nqt;
  const int h = bh & 15, b = bh >> 4;
  const int kvh = h >> 2;
  const int lane = threadIdx.x;
  const int lg = lane >> 4, li = lane & 15;
  const int q0 = qt * 16;

  const u16* qb = qh + ((size_t)(b * 16 + h) * S + q0) * 64;
  const u16* kbp = kh + (size_t)(b * 4 + kvh) * S * 64;
  const u16* vb = vt + (size_t)(b * 4 + kvh) * 64 * S;

  const bf16x8 qf0 = *(const bf16x8*)&qb[li * 64 + lg * 8];
  const bf16x8 qf1 = *(const bf16x8*)&qb[li * 64 + 32 + lg * 8];

  const f32x4 fz = {0.f, 0.f, 0.f, 0.f};
  f32x4 o[4];
  float mrow[4], lrow[4];
#pragma unroll
  for (int j = 0; j < 4; j++) o[j] = fz;
#pragma unroll
  for (int r = 0; r < 4; r++) { mrow[r] = -1e30f; lrow[r] = 0.f; }

  __shared__ u16 Ps[16][40];

  const int qmax = q0 + 15;
  for (int kb = 0; kb <= qmax; kb += 32) {
    f32x4 s0 = fz, s1 = fz;
    {
      const u16* kp0 = &kbp[(kb + li) * 64 + lg * 8];
      bf16x8 ka = *(const bf16x8*)kp0;
      bf16x8 kc = *(const bf16x8*)(kp0 + 32);
      s0 = mfma16(qf0, ka, s0);
      s0 = mfma16(qf1, kc, s0);
      const u16* kp1 = &kbp[(kb + 16 + li) * 64 + lg * 8];
      ka = *(const bf16x8*)kp1;
      kc = *(const bf16x8*)(kp1 + 32);
      s1 = mfma16(qf0, ka, s1);
      s1 = mfma16(qf1, kc, s1);
    }
#pragma unroll
    for (int r = 0; r < 4; r++) {
      const int qrow = q0 + lg * 4 + r;
      float a = s0[r] * 0.125f;
      float bv = s1[r] * 0.125f;
      if (kb + li > qrow) a = -1e30f;
      if (kb + 16 + li > qrow) bv = -1e30f;
      float mx = fmaxf(a, bv);
      mx = fmaxf(mx, __shfl_xor(mx, 1));
      mx = fmaxf(mx, __shfl_xor(mx, 2));
      mx = fmaxf(mx, __shfl_xor(mx, 4));
      mx = fmaxf(mx, __shfl_xor(mx, 8));
      const float mnew = fmaxf(mrow[r], mx);
      const float corr = __expf(mrow[r] - mnew);
      mrow[r] = mnew;
      const float p0 = __expf(a - mnew);
      const float p1 = __expf(bv - mnew);
      Ps[lg * 4 + r][li] = f2bf(p0);
      Ps[lg * 4 + r][16 + li] = f2bf(p1);
      float ps = p0 + p1;
      ps += __shfl_xor(ps, 1);
      ps += __shfl_xor(ps, 2);
      ps += __shfl_xor(ps, 4);
      ps += __shfl_xor(ps, 8);
      lrow[r] = lrow[r] * corr + ps;
      o[0][r] *= corr;
      o[1][r] *= corr;
      o[2][r] *= corr;
      o[3][r] *= corr;
    }
    __syncthreads();
    const bf16x8 pa = *(const bf16x8*)&Ps[li][lg * 8];
#pragma unroll
    for (int j = 0; j < 4; j++) {
      bf16x8 vf = *(const bf16x8*)&vb[(size_t)(j * 16 + li) * S + kb + lg * 8];
      o[j] = mfma16(pa, vf, o[j]);
    }
    __syncthreads();
  }
#pragma unroll
  for (int j = 0; j < 4; j++)
#pragma unroll
    for (int r = 0; r < 4; r++) {
      const int qrow = q0 + lg * 4 + r;
      y[((size_t)(b * S + qrow)) * 1024 + h * 64 + j * 16 + li] =
          f2bf(o[j][r] / lrow[r]);
    }
}

extern "C" void kernel_launch(void* const* d_in, const int* in_sizes, int n_in,
                              void* d_out, int out_size, void* d_ws, size_t ws_size,
                              hipStream_t stream) {
  const float* x  = (const float*)d_in[0];   // [2][2048][1024]
  const float* Wq = (const float*)d_in[1];   // [1024][1024]
  const float* Wk = (const float*)d_in[2];   // [256][1024]
  const float* Wv = (const float*)d_in[3];   // [256][1024]
  const float* Wp = (const float*)d_in[4];   // [1024][1024]
  const float* qg = (const float*)d_in[5];   // [16]
  float* out = (float*)d_out;                // [4096][1024] f32

  const int S = 2048;
  char* ws = (char*)d_ws;
  // workspace layout (bytes)
  u16*   xb   = (u16*)(ws + 0);            // 4096*1024 bf16   (8 MB)
  u16*   wqb  = (u16*)(ws + 8388608);      // 1024*1024 bf16   (2 MB)
  u16*   wkvb = (u16*)(ws + 10485760);     // 512*1024 bf16    (1 MB)
  u16*   wpb  = (u16*)(ws + 11534336);     // 1024*1024 bf16   (2 MB)
  float* qf   = (float*)(ws + 13631488);   // 4096*1024 f32    (16 MB)
  float* kvf  = (float*)(ws + 30408704);   // 4096*512 f32     (8 MB)
  u16*   qhb  = (u16*)(ws + 38797312);     // [2][16][2048][64] (8 MB)
  u16*   khb  = (u16*)(ws + 47185920);     // [2][4][2048][64]  (2 MB)
  u16*   vtb  = (u16*)(ws + 49283072);     // [2][4][64][2048]  (2 MB)
  u16*   yb   = (u16*)(ws + 51380224);     // 4096*1024 bf16   (8 MB)
  if (ws_size < 59768832) return;

  // casts
  castf2b<<<16384, 256, 0, stream>>>(x, xb, 4194304);
  castf2b<<<4096, 256, 0, stream>>>(Wq, wqb, 1048576);
  castf2b<<<1024, 256, 0, stream>>>(Wk, wkvb, 262144);
  castf2b<<<1024, 256, 0, stream>>>(Wv, wkvb + 262144, 262144);
  castf2b<<<4096, 256, 0, stream>>>(Wp, wpb, 1048576);

  // projections: q = x Wq^T ; [k|v] = x [Wk|Wv]^T
  gemm_bt<<<dim3(8, 32), 256, 0, stream>>>(xb, wqb, qf, 4096, 1024, 1024);
  gemm_bt<<<dim3(4, 32), 256, 0, stream>>>(xb, wkvb, kvf, 4096, 512, 1024);

  // RMSNorm + RoPE (+gain for q), to head-major bf16
  rmsrope<<<dim3(4096, 16), 64, 0, stream>>>(qf, 1024, 16, qg, qhb, S);
  rmsrope<<<dim3(4096, 4), 64, 0, stream>>>(kvf, 512, 4, nullptr, khb, S);
  vcast<<<4096, 256, 0, stream>>>(kvf, vtb, S);

  // causal GQA flash attention
  attn<<<4096, 64, 0, stream>>>(qhb, khb, vtb, yb, S);

  // output projection
  gemm_bt<<<dim3(8, 32), 256, 0, stream>>>(yb, wpb, out, 4096, 1024, 1024);
}

// Round 2
// 370.807 us; speedup vs baseline: 1.0028x; 1.0028x over previous
//
#include <hip/hip_runtime.h>

typedef unsigned short u16;
typedef __bf16 bf16_t;
typedef bf16_t bf16x8 __attribute__((ext_vector_type(8)));
typedef float f32x4 __attribute__((ext_vector_type(4)));
typedef u16 u16x8 __attribute__((ext_vector_type(8)));

__device__ __forceinline__ u16 f2bf(float f) {
  unsigned u = __float_as_uint(f);
  u += 0x7fffu + ((u >> 16) & 1u);
  return (u16)(u >> 16);
}

__device__ __forceinline__ unsigned pk2(float a, float b) {
  return (unsigned)f2bf(a) | ((unsigned)f2bf(b) << 16);
}

__device__ __forceinline__ f32x4 mfma16(bf16x8 a, bf16x8 b, f32x4 c) {
  return __builtin_amdgcn_mfma_f32_16x16x32_bf16(a, b, c, 0, 0, 0);
}

// ---------------- fp32 -> bf16 cast ----------------
__global__ __launch_bounds__(256) void castf2b(const float* __restrict__ in,
                                               u16* __restrict__ out, int n) {
  int i = blockIdx.x * 256 + threadIdx.x;
  if (i < n) out[i] = f2bf(in[i]);
}

// ---------------- GEMM: C[M][N] = A[M][K] * B[N][K]^T ----------------
__global__ __launch_bounds__(256) void gemm_bt(const u16* __restrict__ A,
                                               const u16* __restrict__ B,
                                               float* __restrict__ C,
                                               int M, int N, int K) {
  __shared__ u16 As[128][40];
  __shared__ u16 Bs[128][40];
  const int tid = threadIdx.x;
  const int lane = tid & 63;
  const int lg = lane >> 4, li = lane & 15;
  const int wave = tid >> 6;
  const int wr = (wave >> 1) * 64, wc = (wave & 1) * 64;
  const int m0 = blockIdx.y * 128, n0 = blockIdx.x * 128;
  const int lr = tid >> 1, lc = (tid & 1) * 16;

  const f32x4 fz = {0.f, 0.f, 0.f, 0.f};
  f32x4 acc[4][4];
#pragma unroll
  for (int i = 0; i < 4; i++)
#pragma unroll
    for (int j = 0; j < 4; j++) acc[i][j] = fz;

  for (int k0 = 0; k0 < K; k0 += 32) {
    const u16* ag = &A[(size_t)(m0 + lr) * K + k0 + lc];
    const u16* bg = &B[(size_t)(n0 + lr) * K + k0 + lc];
    *(u16x8*)&As[lr][lc] = *(const u16x8*)ag;
    *(u16x8*)&As[lr][lc + 8] = *(const u16x8*)(ag + 8);
    *(u16x8*)&Bs[lr][lc] = *(const u16x8*)bg;
    *(u16x8*)&Bs[lr][lc + 8] = *(const u16x8*)(bg + 8);
    __syncthreads();
    bf16x8 af[4], bfr[4];
#pragma unroll
    for (int i = 0; i < 4; i++)
      af[i] = *(const bf16x8*)&As[wr + i * 16 + li][lg * 8];
#pragma unroll
    for (int j = 0; j < 4; j++)
      bfr[j] = *(const bf16x8*)&Bs[wc + j * 16 + li][lg * 8];
#pragma unroll
    for (int i = 0; i < 4; i++)
#pragma unroll
      for (int j = 0; j < 4; j++) acc[i][j] = mfma16(af[i], bfr[j], acc[i][j]);
    __syncthreads();
  }
#pragma unroll
  for (int i = 0; i < 4; i++)
#pragma unroll
    for (int j = 0; j < 4; j++)
#pragma unroll
      for (int r = 0; r < 4; r++)
        C[(size_t)(m0 + wr + i * 16 + lg * 4 + r) * N + n0 + wc + j * 16 + li] =
            acc[i][j][r];
}

// ---------------- fused RMSNorm + RoPE + gain, scatter to head-major bf16 ----
__global__ __launch_bounds__(64) void rmsrope(const float* __restrict__ in, int ld,
                                              int nh, const float* __restrict__ gain,
                                              u16* __restrict__ out, int S) {
  const int row = blockIdx.x;  // b*S + s
  const int h = blockIdx.y;
  const int t = threadIdx.x;   // 0..63
  const float v = in[(size_t)row * ld + h * 64 + t];
  float ss = v * v;
#pragma unroll
  for (int m = 1; m < 64; m <<= 1) ss += __shfl_xor(ss, m);
  const float vn = v * rsqrtf(ss * (1.0f / 64.0f) + 1.1920929e-07f);
  const float partner = __shfl_xor(vn, 32);
  const int i = t & 31;
  const float inv = powf(10000.0f, -(float)(2 * i) / 64.0f);
  const int b = row / S;
  const int s = row - b * S;
  const float fr = (float)s * inv;
  float sn, cs;
  sincosf(fr, &sn, &cs);
  float o = (t < 32) ? (vn * cs + partner * sn) : (vn * cs - partner * sn);
  if (gain) o *= gain[h];
  out[((size_t)(b * nh + h) * S + s) * 64 + t] = f2bf(o);
}

// ---------------- V cast+transpose: kvf[B*S][512] cols 256..511 -> [B][4][64][S]
__global__ __launch_bounds__(256) void vcast(const float* __restrict__ kvf,
                                             u16* __restrict__ vt, int S) {
  int idx = blockIdx.x * 256 + threadIdx.x;
  int row = idx >> 8;
  int c = idx & 255;
  int b = row / S, s = row - b * S;
  int kv = c >> 6, d = c & 63;
  vt[((size_t)(b * 4 + kv) * 64 + d) * S + s] = f2bf(kvf[(size_t)row * 512 + 256 + c]);
}

// ---------------- flash attention v2: 4 waves/block, swapped QK^T, KVBLK=64 --
// qh: [B][16][S][64], kh: [B][4][S][64], vt: [B][4][64][S], y: [B*S][1024]
__global__ __launch_bounds__(256) void attn2(const u16* __restrict__ qh,
                                             const u16* __restrict__ kh,
                                             const u16* __restrict__ vt,
                                             u16* __restrict__ y, int S) {
  const int nqb = S >> 6;                       // 64-row q blocks
  const int qb = (nqb - 1) - (blockIdx.x % nqb);  // heavy blocks first
  const int bh = blockIdx.x / nqb;
  const int h = bh & 15, b = bh >> 4;
  const int kvh = h >> 2;
  const int tid = threadIdx.x;
  const int wave = tid >> 6;
  const int lane = tid & 63;
  const int lg = lane >> 4, li = lane & 15;
  const int q0 = qb * 64 + wave * 16;           // this wave's 16 q rows

  const u16* qp = qh + ((size_t)(b * 16 + h) * S + q0) * 64;
  const u16* kp = kh + (size_t)(b * 4 + kvh) * S * 64;
  const u16* vp = vt + (size_t)(b * 4 + kvh) * 64 * S;

  // Q as B-operand: col = q row (li), k = lg*8+j
  const bf16x8 qf0 = *(const bf16x8*)&qp[li * 64 + lg * 8];
  const bf16x8 qf1 = *(const bf16x8*)&qp[li * 64 + 32 + lg * 8];

  // per-wave P buffer: 16 rows x 64 keys bf16, XOR-swizzled 16B blocks
  __shared__ __align__(16) u16 Ps[4][16][64];
  char* psrow = (char*)&Ps[wave][li][0];
  const int swz = li & 7;

  const f32x4 fz = {0.f, 0.f, 0.f, 0.f};
  f32x4 o[4];
#pragma unroll
  for (int j = 0; j < 4; j++) o[j] = fz;
  float mrow = -1e30f, lrow = 0.f;  // state for q row (q0 + li)
  const int qrow = q0 + li;

  for (int kb = 0; kb <= q0 + 15; kb += 64) {
    // --- S^T = K · Q^T : s[t] rows = keys kb+t*16+lg*4+r, col = q row li ---
    f32x4 s[4];
#pragma unroll
    for (int t = 0; t < 4; t++) {
      const u16* kr = &kp[(size_t)(kb + t * 16 + li) * 64 + lg * 8];
      bf16x8 ka = *(const bf16x8*)kr;
      bf16x8 kc = *(const bf16x8*)(kr + 32);
      s[t] = mfma16(ka, qf0, fz);
      s[t] = mfma16(kc, qf1, s[t]);
    }
    // --- mask + scale; per-lane: 16 keys of one q row ---
    float pv[16];
#pragma unroll
    for (int t = 0; t < 4; t++)
#pragma unroll
      for (int r = 0; r < 4; r++) {
        float x = s[t][r] * 0.125f;
        pv[t * 4 + r] = (kb + t * 16 + lg * 4 + r > qrow) ? -1e30f : x;
      }
    // --- online softmax: in-lane reduce + 2 shuffles across lg ---
    float mt = pv[0];
#pragma unroll
    for (int i = 1; i < 16; i++) mt = fmaxf(mt, pv[i]);
    mt = fmaxf(mt, __shfl_xor(mt, 16));
    mt = fmaxf(mt, __shfl_xor(mt, 32));
    const float mnew = fmaxf(mrow, mt);
    const float corr = __expf(mrow - mnew);
    mrow = mnew;
    float psum = 0.f;
#pragma unroll
    for (int i = 0; i < 16; i++) {
      pv[i] = __expf(pv[i] - mnew);
      psum += pv[i];
    }
    psum += __shfl_xor(psum, 16);
    psum += __shfl_xor(psum, 32);
    lrow = lrow * corr + psum;
    // --- P -> LDS (bf16, swizzled) ---
#pragma unroll
    for (int t = 0; t < 4; t++) {
      uint2 w;
      w.x = pk2(pv[t * 4 + 0], pv[t * 4 + 1]);
      w.y = pk2(pv[t * 4 + 2], pv[t * 4 + 3]);
      const int c8 = (t * 4 + lg) ^ (swz << 1);
      *(uint2*)(psrow + c8 * 8) = w;
    }
    // --- rescale O by corr (broadcast to PV row layout) ---
#pragma unroll
    for (int r = 0; r < 4; r++) {
      const float cb = __shfl(corr, lg * 4 + r);
      o[0][r] *= cb; o[1][r] *= cb; o[2][r] *= cb; o[3][r] *= cb;
    }
    // --- PV: A = P (row = q idx li, k = key), B = V^T ---
    const bf16x8 pa0 = *(const bf16x8*)(psrow + ((lg + 0) ^ swz) * 16);
    const bf16x8 pa1 = *(const bf16x8*)(psrow + ((lg + 4) ^ swz) * 16);
#pragma unroll
    for (int j = 0; j < 4; j++) {
      const u16* vr = &vp[(size_t)(j * 16 + li) * S + kb];
      bf16x8 v0 = *(const bf16x8*)&vr[lg * 8];
      bf16x8 v1 = *(const bf16x8*)&vr[32 + lg * 8];
      o[j] = mfma16(pa0, v0, o[j]);
      o[j] = mfma16(pa1, v1, o[j]);
    }
  }
  // --- epilogue: divide by l, write out ---
  float linv[4];
#pragma unroll
  for (int r = 0; r < 4; r++) linv[r] = 1.0f / __shfl(lrow, lg * 4 + r);
#pragma unroll
  for (int j = 0; j < 4; j++)
#pragma unroll
    for (int r = 0; r < 4; r++)
      y[((size_t)(b * S + q0 + lg * 4 + r)) * 1024 + h * 64 + j * 16 + li] =
          f2bf(o[j][r] * linv[r]);
}

extern "C" void kernel_launch(void* const* d_in, const int* in_sizes, int n_in,
                              void* d_out, int out_size, void* d_ws, size_t ws_size,
                              hipStream_t stream) {
  const float* x  = (const float*)d_in[0];
  const float* Wq = (const float*)d_in[1];
  const float* Wk = (const float*)d_in[2];
  const float* Wv = (const float*)d_in[3];
  const float* Wp = (const float*)d_in[4];
  const float* qg = (const float*)d_in[5];
  float* out = (float*)d_out;

  const int S = 2048;
  char* ws = (char*)d_ws;
  u16*   xb   = (u16*)(ws + 0);
  u16*   wqb  = (u16*)(ws + 8388608);
  u16*   wkvb = (u16*)(ws + 10485760);
  u16*   wpb  = (u16*)(ws + 11534336);
  float* qf   = (float*)(ws + 13631488);
  float* kvf  = (float*)(ws + 30408704);
  u16*   qhb  = (u16*)(ws + 38797312);
  u16*   khb  = (u16*)(ws + 47185920);
  u16*   vtb  = (u16*)(ws + 49283072);
  u16*   yb   = (u16*)(ws + 51380224);
  if (ws_size < 59768832) return;

  castf2b<<<16384, 256, 0, stream>>>(x, xb, 4194304);
  castf2b<<<4096, 256, 0, stream>>>(Wq, wqb, 1048576);
  castf2b<<<1024, 256, 0, stream>>>(Wk, wkvb, 262144);
  castf2b<<<1024, 256, 0, stream>>>(Wv, wkvb + 262144, 262144);
  castf2b<<<4096, 256, 0, stream>>>(Wp, wpb, 1048576);

  gemm_bt<<<dim3(8, 32), 256, 0, stream>>>(xb, wqb, qf, 4096, 1024, 1024);
  gemm_bt<<<dim3(4, 32), 256, 0, stream>>>(xb, wkvb, kvf, 4096, 512, 1024);

  rmsrope<<<dim3(4096, 16), 64, 0, stream>>>(qf, 1024, 16, qg, qhb, S);
  rmsrope<<<dim3(4096, 4), 64, 0, stream>>>(kvf, 512, 4, nullptr, khb, S);
  vcast<<<4096, 256, 0, stream>>>(kvf, vtb, S);

  attn2<<<1024, 256, 0, stream>>>(qhb, khb, vtb, yb, S);

  gemm_bt<<<dim3(8, 32), 256, 0, stream>>>(yb, wpb, out, 4096, 1024, 1024);
}